// Round 16
// baseline (202.348 us; speedup 1.0000x reference)
//
#include <hip/hip_runtime.h>
#include <hip/hip_bf16.h>

// ---------------------------------------------------------------------------
// EnhancedMultiHeadAttention on MI355X (gfx950)
// B=2, S=2048, D=1024, H=16, dk=64. fp32 in/out, bf16 MFMA compute.
// Round 16: R15 base + K read DIRECTLY from global (L1/L2-resident; guide
// common-mistake #7) — drops K LDS staging entirely, halves LDS read
// traffic. V stays LDS-staged (transpose needed). GEMMs/convert unchanged.
// ---------------------------------------------------------------------------

#define S_LEN 2048
#define D_MODEL 1024
#define NHEADS 16
#define DK 64
#define BATCH 2
#define M_ROWS (BATCH * S_LEN)   // 4096
#define LOG2E 1.4426950408889634f

typedef float f32x4 __attribute__((ext_vector_type(4)));
typedef short s16x8 __attribute__((ext_vector_type(8)));
typedef unsigned short u16x4 __attribute__((ext_vector_type(4)));
typedef unsigned u32x4 __attribute__((ext_vector_type(4)));

__device__ __forceinline__ unsigned short f2bf(float f) {
    unsigned u = __builtin_bit_cast(unsigned, f);
    u = (u + 0x7FFFu + ((u >> 16) & 1u)) >> 16;
    return (unsigned short)u;
}

__device__ __forceinline__ float fast_exp2(float x) {
    float r;
    asm("v_exp_f32 %0, %1" : "=v"(r) : "v"(x));
    return r;
}

__device__ __forceinline__ unsigned cvt_pk_bf16(float a, float b) {
    unsigned r;
    asm("v_cvt_pk_bf16_f32 %0, %1, %2" : "=v"(r) : "v"(a), "v"(b));
    return r;
}

#define GLD16(gptr, lptr)                                                     \
    __builtin_amdgcn_global_load_lds(                                         \
        (const __attribute__((address_space(1))) void*)(gptr),                \
        (__attribute__((address_space(3))) void*)(lptr), 16, 0, 0)

// ---------------------------------------------------------------------------
// fp32 -> bf16 conversion of Q,K,V,Wq,Wk,Wv,Wo + mask table (fused tail)
// ---------------------------------------------------------------------------
__global__ __launch_bounds__(256) void convert_kernel(
    const float* __restrict__ Q, const float* __restrict__ K,
    const float* __restrict__ V,
    const float* __restrict__ Wq, const float* __restrict__ Wk,
    const float* __restrict__ Wv, const float* __restrict__ Wo,
    unsigned short* __restrict__ Qb, unsigned short* __restrict__ Kb,
    unsigned short* __restrict__ Vb,
    unsigned short* __restrict__ Wqb, unsigned short* __restrict__ Wkb,
    unsigned short* __restrict__ Wvb, unsigned short* __restrict__ Wob,
    float* __restrict__ mtab)
{
    const int XN = M_ROWS * D_MODEL / 8;    // 524288
    const int WN = D_MODEL * D_MODEL / 8;   // 131072
    const int TOT = 3 * XN + 4 * WN;        // 2097152
    int i = blockIdx.x * 256 + threadIdx.x;
    if (i >= TOT) {
        int d = i - TOT;
        if (d < S_LEN) {
            float d2 = (float)d * (float)d;
            mtab[d] = LOG2E * 0.25f * (__expf(-d2 * (1.0f / 50.0f)) +
                                       __expf(-d2 * (1.0f / 200.0f)) +
                                       __expf(-d2 * (1.0f / 800.0f)) +
                                       __expf(-d2 * (1.0f / 3200.0f)));
        }
        return;
    }
    const float* src;
    unsigned short* dst;
    int off;
    if (i < 3 * XN) {
        if (i < XN)          { src = Q; dst = Qb; off = i; }
        else if (i < 2 * XN) { src = K; dst = Kb; off = i - XN; }
        else                 { src = V; dst = Vb; off = i - 2 * XN; }
    } else {
        int j = i - 3 * XN;
        if (j < WN)          { src = Wq; dst = Wqb; off = j; }
        else if (j < 2 * WN) { src = Wk; dst = Wkb; off = j - WN; }
        else if (j < 3 * WN) { src = Wv; dst = Wvb; off = j - 2 * WN; }
        else                 { src = Wo; dst = Wob; off = j - 3 * WN; }
    }
    f32x4 v0 = *(const f32x4*)(src + (size_t)off * 8);
    f32x4 v1 = *(const f32x4*)(src + (size_t)off * 8 + 4);
    s16x8 o;
#pragma unroll
    for (int j = 0; j < 4; ++j) {
        o[j]     = (short)f2bf(v0[j]);
        o[j + 4] = (short)f2bf(v1[j]);
    }
    *(s16x8*)(dst + (size_t)off * 8) = o;
}

// ---------------------------------------------------------------------------
// m97-structure GEMM core: C[128x128] = A[128xK] @ B[128xK]^T  (bf16 inputs)
// ---------------------------------------------------------------------------
__device__ __forceinline__ void gemm_core_128(
    const unsigned short* __restrict__ A, const unsigned short* __restrict__ B,
    unsigned short* As, unsigned short* Bs,
    int m0, int n0, int K, int tid, f32x4 acc[4][4])
{
    const int wid  = tid >> 6;
    const int lane = tid & 63;
    const int g    = lane >> 4;
    const int c    = lane & 15;
    const int wm   = wid >> 1;
    const int wn   = wid & 1;

    const int srow   = tid >> 3;
    const int schunk = tid & 7;

    for (int kt = 0; kt < K / 64; ++kt) {
        const int k0 = kt * 64;
        __syncthreads();
#pragma unroll
        for (int r = 0; r < 4; ++r) {
            const int row = r * 32 + srow;
            GLD16(A + (size_t)(m0 + row) * K + k0 + schunk * 8,
                  &As[(r * 256 + wid * 64) * 8]);
        }
#pragma unroll
        for (int r = 0; r < 4; ++r) {
            const int row = r * 32 + srow;
            GLD16(B + (size_t)(n0 + row) * K + k0 + schunk * 8,
                  &Bs[(r * 256 + wid * 64) * 8]);
        }
        __syncthreads();

        s16x8 a[2][4];
#pragma unroll
        for (int ks = 0; ks < 2; ++ks)
#pragma unroll
            for (int mf = 0; mf < 4; ++mf)
                a[ks][mf] = *(const s16x8*)
                    &As[(wm * 64 + mf * 16 + c) * 64 + ks * 32 + g * 8];
#pragma unroll
        for (int ks = 0; ks < 2; ++ks) {
#pragma unroll
            for (int nf = 0; nf < 4; ++nf) {
                s16x8 b = *(const s16x8*)
                    &Bs[(wn * 64 + nf * 16 + c) * 64 + ks * 32 + g * 8];
#pragma unroll
                for (int mf = 0; mf < 4; ++mf)
                    acc[mf][nf] = __builtin_amdgcn_mfma_f32_16x16x32_bf16(
                        a[ks][mf], b, acc[mf][nf], 0, 0, 0);
            }
        }
    }
}

// ---------------------------------------------------------------------------
// QKV projection: Y = X @ W^T + b -> bf16 head layout [B][H][S][dk]
// ---------------------------------------------------------------------------
__global__ __launch_bounds__(256) void proj_gemm(
    const unsigned short* __restrict__ Qx, const unsigned short* __restrict__ Kx,
    const unsigned short* __restrict__ Vx,
    const unsigned short* __restrict__ Wq, const unsigned short* __restrict__ Wk,
    const unsigned short* __restrict__ Wv,
    const float* __restrict__ bq, const float* __restrict__ bk,
    const float* __restrict__ bv,
    unsigned short* __restrict__ qo, unsigned short* __restrict__ ko,
    unsigned short* __restrict__ vo)
{
    const int z = blockIdx.z;
    const unsigned short* X = (z == 0) ? Qx : (z == 1) ? Kx : Vx;
    const unsigned short* W = (z == 0) ? Wq : (z == 1) ? Wk : Wv;
    const float* bias       = (z == 0) ? bq : (z == 1) ? bk : bv;
    unsigned short* out     = (z == 0) ? qo : (z == 1) ? ko : vo;
    const float scale = (z == 0) ? (0.125f * LOG2E) : 1.0f;

    __shared__ unsigned short As[128 * 64];
    __shared__ unsigned short Bs[128 * 64];

    const int tid = threadIdx.x;
    const int flat = blockIdx.y * 32 + blockIdx.x;
    const int sw   = (flat & 7) * 32 + (flat >> 3);
    const int m0   = (sw & 31) * 128;
    const int n0   = (sw >> 5) * 128;

    f32x4 acc[4][4];
#pragma unroll
    for (int i = 0; i < 4; ++i)
#pragma unroll
        for (int j = 0; j < 4; ++j) acc[i][j] = (f32x4){0.f, 0.f, 0.f, 0.f};

    gemm_core_128(X, W, As, Bs, m0, n0, D_MODEL, tid, acc);

    const int lane = tid & 63;
    const int g    = lane >> 4;
    const int c    = lane & 15;
    const int wm   = (tid >> 6) >> 1;
    const int wn   = (tid >> 6) & 1;

#pragma unroll
    for (int mf = 0; mf < 4; ++mf) {
#pragma unroll
        for (int nf = 0; nf < 4; ++nf) {
            const int o = n0 + wn * 64 + nf * 16 + c;
            const float bv_ = bias[o];
            const int h  = o >> 6;
            const int dd = o & 63;
#pragma unroll
            for (int r = 0; r < 4; ++r) {
                const int m = m0 + wm * 64 + mf * 16 + g * 4 + r;
                const int b = m >> 11;
                const int s = m & (S_LEN - 1);
                const float val = (acc[mf][nf][r] + bv_) * scale;
                out[(((size_t)(b * NHEADS + h)) * S_LEN + s) * DK + dd] = f2bf(val);
            }
        }
    }
}

// ---------------------------------------------------------------------------
// Output projection: Y = A @ Wo^T + bo  (fp32 out)
// ---------------------------------------------------------------------------
__global__ __launch_bounds__(256) void out_gemm(
    const unsigned short* __restrict__ A,
    const unsigned short* __restrict__ W,
    const float* __restrict__ bias,
    float* __restrict__ out)
{
    __shared__ unsigned short As[128 * 64];
    __shared__ unsigned short Bs[128 * 64];

    const int tid = threadIdx.x;
    const int flat = blockIdx.y * 32 + blockIdx.x;
    const int sw   = (flat & 7) * 32 + (flat >> 3);
    const int m0   = (sw & 31) * 128;
    const int n0   = (sw >> 5) * 128;

    f32x4 acc[4][4];
#pragma unroll
    for (int i = 0; i < 4; ++i)
#pragma unroll
        for (int j = 0; j < 4; ++j) acc[i][j] = (f32x4){0.f, 0.f, 0.f, 0.f};

    gemm_core_128(A, W, As, Bs, m0, n0, D_MODEL, tid, acc);

    const int lane = tid & 63;
    const int g    = lane >> 4;
    const int c    = lane & 15;
    const int wm   = (tid >> 6) >> 1;
    const int wn   = (tid >> 6) & 1;

#pragma unroll
    for (int mf = 0; mf < 4; ++mf) {
#pragma unroll
        for (int nf = 0; nf < 4; ++nf) {
            const int o = n0 + wn * 64 + nf * 16 + c;
            const float bv_ = bias[o];
#pragma unroll
            for (int r = 0; r < 4; ++r) {
                const int m = m0 + wm * 64 + mf * 16 + g * 4 + r;
                out[(size_t)m * D_MODEL + o] = acc[mf][nf][r] + bv_;
            }
        }
    }
}

// ---------------------------------------------------------------------------
// Flash attention: sigma-permuted swapped QK^T with K fragments read
// DIRECTLY from global (L1/L2-resident, no K LDS staging); V staged
// transposed in dbuf LDS. Lane-local P, direct exp2, 1 barrier/tile.
// grid (16, 32) XCD-swizzled -> 512 blocks, 8 waves, 16 q-rows/wave.
// ---------------------------------------------------------------------------
#define VSWZ(row) ((((row) >> 1) & 7) << 4)

__global__ __launch_bounds__(512) void attn_kernel(
    const unsigned short* __restrict__ qh,
    const unsigned short* __restrict__ kh,
    const unsigned short* __restrict__ vh,
    const float* __restrict__ mask_tab,
    unsigned short* __restrict__ attn_out)
{
    __shared__ float mtab[S_LEN];                  // 8 KB
    __shared__ unsigned short Vt[2][64 * 64];      // 16 KB, dbuf V^T [d][k]

    const int tid  = threadIdx.x;
    const int wid  = tid >> 6;
    const int lane = tid & 63;
    const int g    = lane >> 4;
    const int c    = lane & 15;

    // XCD swizzle: nwg = 512, chunk 64 per XCD (= 4 heads' K/V in one L2)
    const int flat = blockIdx.y * 16 + blockIdx.x;
    const int sw   = (flat & 7) * 64 + (flat >> 3);
    const int bh   = sw >> 4;
    const int bx   = sw & 15;
    const int b    = bh >> 4;
    const int h    = bh & 15;
    const int q0w  = bx * 128 + wid * 16;

    *(f32x4*)&mtab[tid * 4] = *(const f32x4*)&mask_tab[tid * 4];

    const size_t head_off = (size_t)bh * S_LEN * DK;
    const unsigned short* qp = qh + head_off;
    const unsigned short* kp = kh + head_off;
    const unsigned short* vp = vh + head_off;

    s16x8 aq[2];
    {
        const unsigned short* qrow = qp + (size_t)(q0w + c) * DK;
        aq[0] = *(const s16x8*)(qrow + g * 8);
        aq[1] = *(const s16x8*)(qrow + 32 + g * 8);
    }

    f32x4 acc_o[4];
#pragma unroll
    for (int nf = 0; nf < 4; ++nf) acc_o[nf] = (f32x4){0.f, 0.f, 0.f, 0.f};
    f32x4 lsum = (f32x4){0.f, 0.f, 0.f, 0.f};

    // sigma'd QK^T rows (per nf, function of c only); per-lane K row base ptr
    const unsigned short* krow_ptr[4];
#pragma unroll
    for (int nf = 0; nf < 4; ++nf) {
        const int row = ((c >> 2) << 3) + ((nf & 1) << 2) + (c & 3) + ((nf >> 1) << 5);
        krow_ptr[nf] = kp + (size_t)row * DK + g * 8;
    }

    // V staging roles (512 threads; 64x64 shorts)
    const int vd0 = (tid & 31) * 2;    // d row pair
    const int vkq = (tid >> 5) * 4;    // k quad

    unsigned vreg[4];

    // ---- prologue: V tile 0 -> regs -> buf0; prefetch V tile 1 -> regs ----
#pragma unroll
    for (int i = 0; i < 4; ++i)
        vreg[i] = *(const unsigned*)&vp[(size_t)(vkq + i) * DK + vd0];
    {
        u16x4 lo4, hi4;
#pragma unroll
        for (int i = 0; i < 4; ++i) {
            lo4[i] = (unsigned short)vreg[i];
            hi4[i] = (unsigned short)(vreg[i] >> 16);
        }
        *(u16x4*)((char*)Vt[0] + vd0 * 128 + ((vkq * 2) ^ VSWZ(vd0)))           = lo4;
        *(u16x4*)((char*)Vt[0] + (vd0 + 1) * 128 + ((vkq * 2) ^ VSWZ(vd0 + 1))) = hi4;
    }
#pragma unroll
    for (int i = 0; i < 4; ++i)
        vreg[i] = *(const unsigned*)&vp[(size_t)(64 + vkq + i) * DK + vd0];
    __syncthreads();

    const int NT = S_LEN / 64;
    for (int kt = 0; kt < NT; ++kt) {
        const int k0 = kt * 64;
        const int cur = kt & 1;
        const unsigned short* Vc = Vt[cur];

        // ---- write V tile kt+1 into other buffer (overlaps compute) ----
        if (kt + 1 < NT) {
            unsigned short* Vn = Vt[cur ^ 1];
            u16x4 lo4, hi4;
#pragma unroll
            for (int i = 0; i < 4; ++i) {
                lo4[i] = (unsigned short)vreg[i];
                hi4[i] = (unsigned short)(vreg[i] >> 16);
            }
            *(u16x4*)((char*)Vn + vd0 * 128 + ((vkq * 2) ^ VSWZ(vd0)))           = lo4;
            *(u16x4*)((char*)Vn + (vd0 + 1) * 128 + ((vkq * 2) ^ VSWZ(vd0 + 1))) = hi4;
            if (kt + 2 < NT) {
                const int k2 = k0 + 128;
#pragma unroll
                for (int i = 0; i < 4; ++i)
                    vreg[i] = *(const unsigned*)&vp[(size_t)(k2 + vkq + i) * DK + vd0];
            }
        }

        // ---- K fragments direct from global (L1-resident: 8KB tile x 8
        //      waves reuse). 16B contiguous per lane; issue all 8 early. ----
        s16x8 kfr[4][2];
#pragma unroll
        for (int nf = 0; nf < 4; ++nf) {
            const unsigned short* kr = krow_ptr[nf] + (size_t)k0 * DK;
            kfr[nf][0] = *(const s16x8*)(kr);
            kfr[nf][1] = *(const s16x8*)(kr + 32);
        }

        // ---- QK^T (swapped, sigma'd): lane holds q=c,
        //      k = g*8 + (nf&1)*4 + r + (nf>>1)*32 ----
        f32x4 st[4];
        __builtin_amdgcn_s_setprio(1);
#pragma unroll
        for (int nf = 0; nf < 4; ++nf) {
            st[nf] = __builtin_amdgcn_mfma_f32_16x16x32_bf16(
                kfr[nf][0], aq[0], (f32x4){0.f, 0.f, 0.f, 0.f}, 0, 0, 0);
            st[nf] = __builtin_amdgcn_mfma_f32_16x16x32_bf16(
                kfr[nf][1], aq[1], st[nf], 0, 0, 0);
        }
        __builtin_amdgcn_s_setprio(0);

        // ---- mask add (near-diagonal tiles only) ----
        const int diff = q0w - k0;
        if (diff >= -15 && diff <= 510) {
            const int dbase = q0w + c - k0 - g * 8;
#pragma unroll
            for (int nf = 0; nf < 4; ++nf) {
                const int koff = ((nf & 1) << 2) + ((nf >> 1) << 5);
#pragma unroll
                for (int r = 0; r < 4; ++r) {
                    const int d = dbase - koff - r;
                    if (d >= 0) st[nf][r] += mtab[d];
                }
            }
        }

        // ---- P = exp2(st) directly; l accumulation ----
#pragma unroll
        for (int nf = 0; nf < 4; ++nf)
#pragma unroll
            for (int r = 0; r < 4; ++r)
                st[nf][r] = fast_exp2(st[nf][r]);
        lsum += (st[0] + st[1]) + (st[2] + st[3]);

        // ---- PV: P lane-local as A-fragment; pack + mfma ----
        __builtin_amdgcn_s_setprio(1);
#pragma unroll
        for (int f = 0; f < 2; ++f) {
            u32x4 w;
            w[0] = cvt_pk_bf16(st[2 * f][0],     st[2 * f][1]);
            w[1] = cvt_pk_bf16(st[2 * f][2],     st[2 * f][3]);
            w[2] = cvt_pk_bf16(st[2 * f + 1][0], st[2 * f + 1][1]);
            w[3] = cvt_pk_bf16(st[2 * f + 1][2], st[2 * f + 1][3]);
            s16x8 pa = __builtin_bit_cast(s16x8, w);
#pragma unroll
            for (int nf = 0; nf < 4; ++nf) {
                const int row = nf * 16 + c;
                s16x8 vb = *(const s16x8*)((const char*)Vc + row * 128 +
                                           ((f * 64 + g * 16) ^ VSWZ(row)));
                acc_o[nf] = __builtin_amdgcn_mfma_f32_16x16x32_bf16(
                    pa, vb, acc_o[nf], 0, 0, 0);
            }
        }
        __builtin_amdgcn_s_setprio(0);

        __syncthreads();   // V writes of t+1 done, reads of t done
    }

    // epilogue: reduce l, normalize, store bf16
    float l = (lsum[0] + lsum[1]) + (lsum[2] + lsum[3]);
    l += __shfl_xor(l, 16);
    l += __shfl_xor(l, 32);
    f32x4 linv;
#pragma unroll
    for (int r = 0; r < 4; ++r) linv[r] = 1.0f / __shfl(l, g * 4 + r);
#pragma unroll
    for (int nf = 0; nf < 4; ++nf) {
#pragma unroll
        for (int r = 0; r < 4; ++r) {
            const int i_glob = q0w + g * 4 + r;
            const int d = nf * 16 + c;
            attn_out[((size_t)(b * S_LEN + i_glob)) * D_MODEL + h * DK + d] =
                f2bf(acc_o[nf][r] * linv[r]);
        }
    }
}

// ---------------------------------------------------------------------------
extern "C" void kernel_launch(void* const* d_in, const int* in_sizes, int n_in,
                              void* d_out, int out_size, void* d_ws, size_t ws_size,
                              hipStream_t stream) {
    const float* Q  = (const float*)d_in[0];
    const float* K  = (const float*)d_in[1];
    const float* V  = (const float*)d_in[2];
    const float* Wq = (const float*)d_in[3];
    const float* bq = (const float*)d_in[4];
    const float* Wk = (const float*)d_in[5];
    const float* bk = (const float*)d_in[6];
    const float* Wv = (const float*)d_in[7];
    const float* bv = (const float*)d_in[8];
    const float* Wo = (const float*)d_in[9];
    const float* bo = (const float*)d_in[10];
    float* out = (float*)d_out;

    const size_t XE = (size_t)M_ROWS * D_MODEL;
    const size_t WE = (size_t)D_MODEL * D_MODEL;
    unsigned short* qh  = (unsigned short*)d_ws;
    unsigned short* kh  = qh + XE;
    unsigned short* vh  = kh + XE;
    unsigned short* ah  = vh + XE;
    unsigned short* Qb  = ah + XE;
    unsigned short* Kb  = Qb + XE;
    unsigned short* Vb  = Kb + XE;
    unsigned short* Wqb = Vb + XE;
    unsigned short* Wkb = Wqb + WE;
    unsigned short* Wvb = Wkb + WE;
    unsigned short* Wob = Wvb + WE;
    float* mtab = (float*)(Wob + WE);

    convert_kernel<<<dim3((3 * XE / 8 + 4 * WE / 8) / 256 + 8), 256, 0, stream>>>(
        Q, K, V, Wq, Wk, Wv, Wo, Qb, Kb, Vb, Wqb, Wkb, Wvb, Wob, mtab);
    proj_gemm<<<dim3(32, 8, 3), 256, 0, stream>>>(
        Qb, Kb, Vb, Wqb, Wkb, Wvb, bq, bk, bv, qh, kh, vh);
    attn_kernel<<<dim3(16, 32), 512, 0, stream>>>(
        qh, kh, vh, mtab, ah);
    out_gemm<<<dim3(32, 8), 256, 0, stream>>>(
        ah, Wob, bo, out);
}

// Round 17
// 128.105 us; speedup vs baseline: 1.5795x; 1.5795x over previous
//
#include <hip/hip_runtime.h>
#include <hip/hip_bf16.h>

// ---------------------------------------------------------------------------
// EnhancedMultiHeadAttention on MI355X (gfx950)
// B=2, S=2048, D=1024, H=16, dk=64. fp32 in/out, bf16 MFMA compute.
// Round 17: exact revert to R15/R11 (best: 128.1us, reproduced twice).
// R16's direct-global K was a latency disaster (uncoalesced 16B scatter,
// MfmaUtil 10%): LDS staging converts one coalesced load into conflict-
// free low-latency rereads — that, not capacity, is its value here.
// attn = sigma-permuted swapped QK^T, lane-local P, direct exp2,
// dbuf + 1 barrier/tile, split swizzles (K bit3-folded, V (row>>1)&7),
// XCD swizzle. GEMMs = m97 128^2 structure. convert = HBM-bound pass.
// ---------------------------------------------------------------------------

#define S_LEN 2048
#define D_MODEL 1024
#define NHEADS 16
#define DK 64
#define BATCH 2
#define M_ROWS (BATCH * S_LEN)   // 4096
#define LOG2E 1.4426950408889634f

typedef float f32x4 __attribute__((ext_vector_type(4)));
typedef short s16x8 __attribute__((ext_vector_type(8)));
typedef unsigned short u16x4 __attribute__((ext_vector_type(4)));
typedef unsigned u32x4 __attribute__((ext_vector_type(4)));

__device__ __forceinline__ unsigned short f2bf(float f) {
    unsigned u = __builtin_bit_cast(unsigned, f);
    u = (u + 0x7FFFu + ((u >> 16) & 1u)) >> 16;
    return (unsigned short)u;
}

__device__ __forceinline__ float fast_exp2(float x) {
    float r;
    asm("v_exp_f32 %0, %1" : "=v"(r) : "v"(x));
    return r;
}

__device__ __forceinline__ unsigned cvt_pk_bf16(float a, float b) {
    unsigned r;
    asm("v_cvt_pk_bf16_f32 %0, %1, %2" : "=v"(r) : "v"(a), "v"(b));
    return r;
}

#define GLD16(gptr, lptr)                                                     \
    __builtin_amdgcn_global_load_lds(                                         \
        (const __attribute__((address_space(1))) void*)(gptr),                \
        (__attribute__((address_space(3))) void*)(lptr), 16, 0, 0)

// ---------------------------------------------------------------------------
// fp32 -> bf16 conversion of Q,K,V,Wq,Wk,Wv,Wo + mask table (fused tail)
// ---------------------------------------------------------------------------
__global__ __launch_bounds__(256) void convert_kernel(
    const float* __restrict__ Q, const float* __restrict__ K,
    const float* __restrict__ V,
    const float* __restrict__ Wq, const float* __restrict__ Wk,
    const float* __restrict__ Wv, const float* __restrict__ Wo,
    unsigned short* __restrict__ Qb, unsigned short* __restrict__ Kb,
    unsigned short* __restrict__ Vb,
    unsigned short* __restrict__ Wqb, unsigned short* __restrict__ Wkb,
    unsigned short* __restrict__ Wvb, unsigned short* __restrict__ Wob,
    float* __restrict__ mtab)
{
    const int XN = M_ROWS * D_MODEL / 8;    // 524288
    const int WN = D_MODEL * D_MODEL / 8;   // 131072
    const int TOT = 3 * XN + 4 * WN;        // 2097152
    int i = blockIdx.x * 256 + threadIdx.x;
    if (i >= TOT) {
        int d = i - TOT;
        if (d < S_LEN) {
            float d2 = (float)d * (float)d;
            mtab[d] = LOG2E * 0.25f * (__expf(-d2 * (1.0f / 50.0f)) +
                                       __expf(-d2 * (1.0f / 200.0f)) +
                                       __expf(-d2 * (1.0f / 800.0f)) +
                                       __expf(-d2 * (1.0f / 3200.0f)));
        }
        return;
    }
    const float* src;
    unsigned short* dst;
    int off;
    if (i < 3 * XN) {
        if (i < XN)          { src = Q; dst = Qb; off = i; }
        else if (i < 2 * XN) { src = K; dst = Kb; off = i - XN; }
        else                 { src = V; dst = Vb; off = i - 2 * XN; }
    } else {
        int j = i - 3 * XN;
        if (j < WN)          { src = Wq; dst = Wqb; off = j; }
        else if (j < 2 * WN) { src = Wk; dst = Wkb; off = j - WN; }
        else if (j < 3 * WN) { src = Wv; dst = Wvb; off = j - 2 * WN; }
        else                 { src = Wo; dst = Wob; off = j - 3 * WN; }
    }
    f32x4 v0 = *(const f32x4*)(src + (size_t)off * 8);
    f32x4 v1 = *(const f32x4*)(src + (size_t)off * 8 + 4);
    s16x8 o;
#pragma unroll
    for (int j = 0; j < 4; ++j) {
        o[j]     = (short)f2bf(v0[j]);
        o[j + 4] = (short)f2bf(v1[j]);
    }
    *(s16x8*)(dst + (size_t)off * 8) = o;
}

// ---------------------------------------------------------------------------
// m97-structure GEMM core: C[128x128] = A[128xK] @ B[128xK]^T  (bf16 inputs)
// ---------------------------------------------------------------------------
__device__ __forceinline__ void gemm_core_128(
    const unsigned short* __restrict__ A, const unsigned short* __restrict__ B,
    unsigned short* As, unsigned short* Bs,
    int m0, int n0, int K, int tid, f32x4 acc[4][4])
{
    const int wid  = tid >> 6;
    const int lane = tid & 63;
    const int g    = lane >> 4;
    const int c    = lane & 15;
    const int wm   = wid >> 1;
    const int wn   = wid & 1;

    const int srow   = tid >> 3;
    const int schunk = tid & 7;

    for (int kt = 0; kt < K / 64; ++kt) {
        const int k0 = kt * 64;
        __syncthreads();
#pragma unroll
        for (int r = 0; r < 4; ++r) {
            const int row = r * 32 + srow;
            GLD16(A + (size_t)(m0 + row) * K + k0 + schunk * 8,
                  &As[(r * 256 + wid * 64) * 8]);
        }
#pragma unroll
        for (int r = 0; r < 4; ++r) {
            const int row = r * 32 + srow;
            GLD16(B + (size_t)(n0 + row) * K + k0 + schunk * 8,
                  &Bs[(r * 256 + wid * 64) * 8]);
        }
        __syncthreads();

        s16x8 a[2][4];
#pragma unroll
        for (int ks = 0; ks < 2; ++ks)
#pragma unroll
            for (int mf = 0; mf < 4; ++mf)
                a[ks][mf] = *(const s16x8*)
                    &As[(wm * 64 + mf * 16 + c) * 64 + ks * 32 + g * 8];
#pragma unroll
        for (int ks = 0; ks < 2; ++ks) {
#pragma unroll
            for (int nf = 0; nf < 4; ++nf) {
                s16x8 b = *(const s16x8*)
                    &Bs[(wn * 64 + nf * 16 + c) * 64 + ks * 32 + g * 8];
#pragma unroll
                for (int mf = 0; mf < 4; ++mf)
                    acc[mf][nf] = __builtin_amdgcn_mfma_f32_16x16x32_bf16(
                        a[ks][mf], b, acc[mf][nf], 0, 0, 0);
            }
        }
    }
}

// ---------------------------------------------------------------------------
// QKV projection: Y = X @ W^T + b -> bf16 head layout [B][H][S][dk]
// ---------------------------------------------------------------------------
__global__ __launch_bounds__(256) void proj_gemm(
    const unsigned short* __restrict__ Qx, const unsigned short* __restrict__ Kx,
    const unsigned short* __restrict__ Vx,
    const unsigned short* __restrict__ Wq, const unsigned short* __restrict__ Wk,
    const unsigned short* __restrict__ Wv,
    const float* __restrict__ bq, const float* __restrict__ bk,
    const float* __restrict__ bv,
    unsigned short* __restrict__ qo, unsigned short* __restrict__ ko,
    unsigned short* __restrict__ vo)
{
    const int z = blockIdx.z;
    const unsigned short* X = (z == 0) ? Qx : (z == 1) ? Kx : Vx;
    const unsigned short* W = (z == 0) ? Wq : (z == 1) ? Wk : Wv;
    const float* bias       = (z == 0) ? bq : (z == 1) ? bk : bv;
    unsigned short* out     = (z == 0) ? qo : (z == 1) ? ko : vo;
    const float scale = (z == 0) ? (0.125f * LOG2E) : 1.0f;

    __shared__ unsigned short As[128 * 64];
    __shared__ unsigned short Bs[128 * 64];

    const int tid = threadIdx.x;
    const int flat = blockIdx.y * 32 + blockIdx.x;
    const int sw   = (flat & 7) * 32 + (flat >> 3);
    const int m0   = (sw & 31) * 128;
    const int n0   = (sw >> 5) * 128;

    f32x4 acc[4][4];
#pragma unroll
    for (int i = 0; i < 4; ++i)
#pragma unroll
        for (int j = 0; j < 4; ++j) acc[i][j] = (f32x4){0.f, 0.f, 0.f, 0.f};

    gemm_core_128(X, W, As, Bs, m0, n0, D_MODEL, tid, acc);

    const int lane = tid & 63;
    const int g    = lane >> 4;
    const int c    = lane & 15;
    const int wm   = (tid >> 6) >> 1;
    const int wn   = (tid >> 6) & 1;

#pragma unroll
    for (int mf = 0; mf < 4; ++mf) {
#pragma unroll
        for (int nf = 0; nf < 4; ++nf) {
            const int o = n0 + wn * 64 + nf * 16 + c;
            const float bv_ = bias[o];
            const int h  = o >> 6;
            const int dd = o & 63;
#pragma unroll
            for (int r = 0; r < 4; ++r) {
                const int m = m0 + wm * 64 + mf * 16 + g * 4 + r;
                const int b = m >> 11;
                const int s = m & (S_LEN - 1);
                const float val = (acc[mf][nf][r] + bv_) * scale;
                out[(((size_t)(b * NHEADS + h)) * S_LEN + s) * DK + dd] = f2bf(val);
            }
        }
    }
}

// ---------------------------------------------------------------------------
// Output projection: Y = A @ Wo^T + bo  (fp32 out)
// ---------------------------------------------------------------------------
__global__ __launch_bounds__(256) void out_gemm(
    const unsigned short* __restrict__ A,
    const unsigned short* __restrict__ W,
    const float* __restrict__ bias,
    float* __restrict__ out)
{
    __shared__ unsigned short As[128 * 64];
    __shared__ unsigned short Bs[128 * 64];

    const int tid = threadIdx.x;
    const int flat = blockIdx.y * 32 + blockIdx.x;
    const int sw   = (flat & 7) * 32 + (flat >> 3);
    const int m0   = (sw & 31) * 128;
    const int n0   = (sw >> 5) * 128;

    f32x4 acc[4][4];
#pragma unroll
    for (int i = 0; i < 4; ++i)
#pragma unroll
        for (int j = 0; j < 4; ++j) acc[i][j] = (f32x4){0.f, 0.f, 0.f, 0.f};

    gemm_core_128(A, W, As, Bs, m0, n0, D_MODEL, tid, acc);

    const int lane = tid & 63;
    const int g    = lane >> 4;
    const int c    = lane & 15;
    const int wm   = (tid >> 6) >> 1;
    const int wn   = (tid >> 6) & 1;

#pragma unroll
    for (int mf = 0; mf < 4; ++mf) {
#pragma unroll
        for (int nf = 0; nf < 4; ++nf) {
            const int o = n0 + wn * 64 + nf * 16 + c;
            const float bv_ = bias[o];
#pragma unroll
            for (int r = 0; r < 4; ++r) {
                const int m = m0 + wm * 64 + mf * 16 + g * 4 + r;
                out[(size_t)m * D_MODEL + o] = acc[mf][nf][r] + bv_;
            }
        }
    }
}

// ---------------------------------------------------------------------------
// Flash attention: sigma-permuted swapped QK^T -> lane-local P for PV.
// grid (16, 32) XCD-swizzled -> 512 blocks, 8 waves, 16 q-rows/wave, KBLK=64.
// K swizzle: bit3-folded; V swizzle: (row>>1)&7. Direct exp2 (no max).
// ---------------------------------------------------------------------------
#define SWZ(row)  ((((row) & 7) ^ ((((row) >> 3) & 1) << 2)) << 4)
#define VSWZ(row) ((((row) >> 1) & 7) << 4)

__global__ __launch_bounds__(512) void attn_kernel(
    const unsigned short* __restrict__ qh,
    const unsigned short* __restrict__ kh,
    const unsigned short* __restrict__ vh,
    const float* __restrict__ mask_tab,
    unsigned short* __restrict__ attn_out)
{
    __shared__ float mtab[S_LEN];                  // 8 KB
    __shared__ unsigned short Kt[2][64 * 64];      // 16 KB, dbuf [k][dk]
    __shared__ unsigned short Vt[2][64 * 64];      // 16 KB, dbuf V^T [d][k]

    const int tid  = threadIdx.x;
    const int wid  = tid >> 6;
    const int lane = tid & 63;
    const int g    = lane >> 4;
    const int c    = lane & 15;

    const int flat = blockIdx.y * 16 + blockIdx.x;
    const int sw   = (flat & 7) * 64 + (flat >> 3);
    const int bh   = sw >> 4;
    const int bx   = sw & 15;
    const int b    = bh >> 4;
    const int h    = bh & 15;
    const int q0w  = bx * 128 + wid * 16;

    *(f32x4*)&mtab[tid * 4] = *(const f32x4*)&mask_tab[tid * 4];

    const size_t head_off = (size_t)bh * S_LEN * DK;
    const unsigned short* qp = qh + head_off;
    const unsigned short* kp = kh + head_off;
    const unsigned short* vp = vh + head_off;

    s16x8 aq[2];
    {
        const unsigned short* qrow = qp + (size_t)(q0w + c) * DK;
        aq[0] = *(const s16x8*)(qrow + g * 8);
        aq[1] = *(const s16x8*)(qrow + 32 + g * 8);
    }

    f32x4 acc_o[4];
#pragma unroll
    for (int nf = 0; nf < 4; ++nf) acc_o[nf] = (f32x4){0.f, 0.f, 0.f, 0.f};
    f32x4 lsum = (f32x4){0.f, 0.f, 0.f, 0.f};

    int krow_nf[4];
#pragma unroll
    for (int nf = 0; nf < 4; ++nf)
        krow_nf[nf] = ((c >> 2) << 3) + ((nf & 1) << 2) + (c & 3) + ((nf >> 1) << 5);

    const int srowK = tid >> 3;
    const int soffE = (tid & 7) * 8;
    const int vd0   = (tid & 31) * 2;
    const int vkq   = (tid >> 5) * 4;

    s16x8 kreg;
    unsigned vreg[4];

    kreg = *(const s16x8*)&kp[(size_t)srowK * DK + soffE];
#pragma unroll
    for (int i = 0; i < 4; ++i)
        vreg[i] = *(const unsigned*)&vp[(size_t)(vkq + i) * DK + vd0];
    {
        *(s16x8*)((char*)Kt[0] + srowK * 128 + ((soffE * 2) ^ SWZ(srowK))) = kreg;
        u16x4 lo4, hi4;
#pragma unroll
        for (int i = 0; i < 4; ++i) {
            lo4[i] = (unsigned short)vreg[i];
            hi4[i] = (unsigned short)(vreg[i] >> 16);
        }
        *(u16x4*)((char*)Vt[0] + vd0 * 128 + ((vkq * 2) ^ VSWZ(vd0)))           = lo4;
        *(u16x4*)((char*)Vt[0] + (vd0 + 1) * 128 + ((vkq * 2) ^ VSWZ(vd0 + 1))) = hi4;
    }
    kreg = *(const s16x8*)&kp[(size_t)(64 + srowK) * DK + soffE];
#pragma unroll
    for (int i = 0; i < 4; ++i)
        vreg[i] = *(const unsigned*)&vp[(size_t)(64 + vkq + i) * DK + vd0];
    __syncthreads();

    const int NT = S_LEN / 64;
    for (int kt = 0; kt < NT; ++kt) {
        const int k0 = kt * 64;
        const int cur = kt & 1;
        const unsigned short* Kc = Kt[cur];
        const unsigned short* Vc = Vt[cur];

        if (kt + 1 < NT) {
            unsigned short* Kn = Kt[cur ^ 1];
            unsigned short* Vn = Vt[cur ^ 1];
            *(s16x8*)((char*)Kn + srowK * 128 + ((soffE * 2) ^ SWZ(srowK))) = kreg;
            u16x4 lo4, hi4;
#pragma unroll
            for (int i = 0; i < 4; ++i) {
                lo4[i] = (unsigned short)vreg[i];
                hi4[i] = (unsigned short)(vreg[i] >> 16);
            }
            *(u16x4*)((char*)Vn + vd0 * 128 + ((vkq * 2) ^ VSWZ(vd0)))           = lo4;
            *(u16x4*)((char*)Vn + (vd0 + 1) * 128 + ((vkq * 2) ^ VSWZ(vd0 + 1))) = hi4;
            if (kt + 2 < NT) {
                const int k2 = k0 + 128;
                kreg = *(const s16x8*)&kp[(size_t)(k2 + srowK) * DK + soffE];
#pragma unroll
                for (int i = 0; i < 4; ++i)
                    vreg[i] = *(const unsigned*)&vp[(size_t)(k2 + vkq + i) * DK + vd0];
            }
        }

        f32x4 st[4];
        __builtin_amdgcn_s_setprio(1);
#pragma unroll
        for (int nf = 0; nf < 4; ++nf) {
            st[nf] = (f32x4){0.f, 0.f, 0.f, 0.f};
            const int row = krow_nf[nf];
#pragma unroll
            for (int f = 0; f < 2; ++f) {
                s16x8 kf = *(const s16x8*)((const char*)Kc + row * 128 +
                                           ((f * 64 + g * 16) ^ SWZ(row)));
                st[nf] = __builtin_amdgcn_mfma_f32_16x16x32_bf16(
                    kf, aq[f], st[nf], 0, 0, 0);
            }
        }
        __builtin_amdgcn_s_setprio(0);

        const int diff = q0w - k0;
        if (diff >= -15 && diff <= 510) {
            const int dbase = q0w + c - k0 - g * 8;
#pragma unroll
            for (int nf = 0; nf < 4; ++nf) {
                const int koff = ((nf & 1) << 2) + ((nf >> 1) << 5);
#pragma unroll
                for (int r = 0; r < 4; ++r) {
                    const int d = dbase - koff - r;
                    if (d >= 0) st[nf][r] += mtab[d];
                }
            }
        }

#pragma unroll
        for (int nf = 0; nf < 4; ++nf)
#pragma unroll
            for (int r = 0; r < 4; ++r)
                st[nf][r] = fast_exp2(st[nf][r]);
        lsum += (st[0] + st[1]) + (st[2] + st[3]);

        __builtin_amdgcn_s_setprio(1);
#pragma unroll
        for (int f = 0; f < 2; ++f) {
            u32x4 w;
            w[0] = cvt_pk_bf16(st[2 * f][0],     st[2 * f][1]);
            w[1] = cvt_pk_bf16(st[2 * f][2],     st[2 * f][3]);
            w[2] = cvt_pk_bf16(st[2 * f + 1][0], st[2 * f + 1][1]);
            w[3] = cvt_pk_bf16(st[2 * f + 1][2], st[2 * f + 1][3]);
            s16x8 pa = __builtin_bit_cast(s16x8, w);
#pragma unroll
            for (int nf = 0; nf < 4; ++nf) {
                const int row = nf * 16 + c;
                s16x8 vb = *(const s16x8*)((const char*)Vc + row * 128 +
                                           ((f * 64 + g * 16) ^ VSWZ(row)));
                acc_o[nf] = __builtin_amdgcn_mfma_f32_16x16x32_bf16(
                    pa, vb, acc_o[nf], 0, 0, 0);
            }
        }
        __builtin_amdgcn_s_setprio(0);

        __syncthreads();
    }

    float l = (lsum[0] + lsum[1]) + (lsum[2] + lsum[3]);
    l += __shfl_xor(l, 16);
    l += __shfl_xor(l, 32);
    f32x4 linv;
#pragma unroll
    for (int r = 0; r < 4; ++r) linv[r] = 1.0f / __shfl(l, g * 4 + r);
#pragma unroll
    for (int nf = 0; nf < 4; ++nf) {
#pragma unroll
        for (int r = 0; r < 4; ++r) {
            const int i_glob = q0w + g * 4 + r;
            const int d = nf * 16 + c;
            attn_out[((size_t)(b * S_LEN + i_glob)) * D_MODEL + h * DK + d] =
                f2bf(acc_o[nf][r] * linv[r]);
        }
    }
}

// ---------------------------------------------------------------------------
extern "C" void kernel_launch(void* const* d_in, const int* in_sizes, int n_in,
                              void* d_out, int out_size, void* d_ws, size_t ws_size,
                              hipStream_t stream) {
    const float* Q  = (const float*)d_in[0];
    const float* K  = (const float*)d_in[1];
    const float* V  = (const float*)d_in[2];
    const float* Wq = (const float*)d_in[3];
    const float* bq = (const float*)d_in[4];
    const float* Wk = (const float*)d_in[5];
    const float* bk = (const float*)d_in[6];
    const float* Wv = (const float*)d_in[7];
    const float* bv = (const float*)d_in[8];
    const float* Wo = (const float*)d_in[9];
    const float* bo = (const float*)d_in[10];
    float* out = (float*)d_out;

    const size_t XE = (size_t)M_ROWS * D_MODEL;
    const size_t WE = (size_t)D_MODEL * D_MODEL;
    unsigned short* qh  = (unsigned short*)d_ws;
    unsigned short* kh  = qh + XE;
    unsigned short* vh  = kh + XE;
    unsigned short* ah  = vh + XE;
    unsigned short* Qb  = ah + XE;
    unsigned short* Kb  = Qb + XE;
    unsigned short* Vb  = Kb + XE;
    unsigned short* Wqb = Vb + XE;
    unsigned short* Wkb = Wqb + WE;
    unsigned short* Wvb = Wkb + WE;
    unsigned short* Wob = Wvb + WE;
    float* mtab = (float*)(Wob + WE);

    convert_kernel<<<dim3((3 * XE / 8 + 4 * WE / 8) / 256 + 8), 256, 0, stream>>>(
        Q, K, V, Wq, Wk, Wv, Wo, Qb, Kb, Vb, Wqb, Wkb, Wvb, Wob, mtab);
    proj_gemm<<<dim3(32, 8, 3), 256, 0, stream>>>(
        Qb, Kb, Vb, Wqb, Wkb, Wvb, bq, bk, bv, qh, kh, vh);
    attn_kernel<<<dim3(16, 32), 512, 0, stream>>>(
        qh, kh, vh, mtab, ah);
    out_gemm<<<dim3(32, 8), 256, 0, stream>>>(
        ah, Wob, bo, out);
}